// Round 1
// baseline (1232.866 us; speedup 1.0000x reference)
//
#include <hip/hip_runtime.h>
#include <math.h>

#define N_TOK 131072
#define K_CB  1024
#define D_DIM 64

// Precompute ||e_k||^2 for all K codebook rows into workspace.
__global__ void en_sq_kernel(const float* __restrict__ emb, float* __restrict__ en) {
    int k = blockIdx.x * blockDim.x + threadIdx.x;
    if (k < K_CB) {
        float s = 0.f;
        #pragma unroll
        for (int d = 0; d < D_DIM; ++d) {
            float v = emb[k * D_DIM + d];
            s = fmaf(v, v, s);
        }
        en[k] = s;
    }
}

// One thread per row: brute-force fp32 argmin over K=1024 (emb read via
// wave-uniform addresses -> scalar loads / SGPR broadcast), then block
// cooperatively writes z_q (gather) and probs (coalesced one-hot float4s).
__global__ __launch_bounds__(256, 2)
void vq_argmin_write_kernel(const float* __restrict__ x,
                            const float* __restrict__ emb,
                            const float* __restrict__ en,
                            float* __restrict__ zq,
                            float* __restrict__ probs) {
    const int tid = threadIdx.x;
    const int base_row = blockIdx.x * 256;
    const int row = base_row + tid;

    // Load this thread's x row into registers (16 x float4).
    float xr[D_DIM];
    const float4* xrow4 = (const float4*)(x + (size_t)row * D_DIM);
    #pragma unroll
    for (int i = 0; i < D_DIM / 4; ++i) {
        float4 v = xrow4[i];
        xr[4*i+0] = v.x; xr[4*i+1] = v.y; xr[4*i+2] = v.z; xr[4*i+3] = v.w;
    }

    float xn = 0.f;
    #pragma unroll
    for (int d = 0; d < D_DIM; ++d) xn = fmaf(xr[d], xr[d], xn);

    float best = INFINITY;
    int bestk = 0;
    for (int k = 0; k < K_CB; ++k) {
        const float* er = emb + k * D_DIM;   // wave-uniform address -> s_load
        float a0 = 0.f, a1 = 0.f, a2 = 0.f, a3 = 0.f;
        #pragma unroll
        for (int d = 0; d < D_DIM; d += 4) {
            a0 = fmaf(xr[d+0], er[d+0], a0);
            a1 = fmaf(xr[d+1], er[d+1], a1);
            a2 = fmaf(xr[d+2], er[d+2], a2);
            a3 = fmaf(xr[d+3], er[d+3], a3);
        }
        float acc = (a0 + a1) + (a2 + a3);
        // round(xn+en) then single-rounded subtract of exact 2*acc, matching
        // (xn + en) - 2*dot elementwise rounding of the reference formula.
        float dist = fmaf(-2.f, acc, xn + en[k]);
        if (dist < best) { best = dist; bestk = k; }   // strict <: first-min wins
    }

    __shared__ int bk_lds[256];
    bk_lds[tid] = bestk;
    __syncthreads();

    // z_q: 256 rows x 16 float4 per block; coalesced stores, gather from
    // L2-resident codebook (256 KB).
    for (int i = tid; i < 256 * (D_DIM / 4); i += 256) {
        int r = i >> 4;        // D_DIM/4 == 16
        int c = i & 15;
        int kk = bk_lds[r];
        float4 v = ((const float4*)(emb + (size_t)kk * D_DIM))[c];
        ((float4*)(zq + (size_t)(base_row + r) * D_DIM))[c] = v;
    }

    // probs: row j is 1024 floats = 256 float4; thread tid writes float4 #tid
    // of each row -> fully coalesced 1 KiB/wave stores.
    for (int j = 0; j < 256; ++j) {
        int kk = bk_lds[j];
        int c = tid * 4;
        float4 v;
        v.x = (kk == c    ) ? 1.f : 0.f;
        v.y = (kk == c + 1) ? 1.f : 0.f;
        v.z = (kk == c + 2) ? 1.f : 0.f;
        v.w = (kk == c + 3) ? 1.f : 0.f;
        ((float4*)(probs + (size_t)(base_row + j) * K_CB))[tid] = v;
    }
}

extern "C" void kernel_launch(void* const* d_in, const int* in_sizes, int n_in,
                              void* d_out, int out_size, void* d_ws, size_t ws_size,
                              hipStream_t stream) {
    const float* x   = (const float*)d_in[0];   // [N, D] fp32
    const float* emb = (const float*)d_in[1];   // [K, D] fp32
    float* zq    = (float*)d_out;                              // [N, D]
    float* probs = (float*)d_out + (size_t)N_TOK * D_DIM;      // [N, K]
    float* en    = (float*)d_ws;                               // [K]

    en_sq_kernel<<<(K_CB + 255) / 256, 256, 0, stream>>>(emb, en);
    vq_argmin_write_kernel<<<N_TOK / 256, 256, 0, stream>>>(x, emb, en, zq, probs);
}